// Round 1
// 129.511 us; speedup vs baseline: 1.0356x; 1.0356x over previous
//
#include <hip/hip_runtime.h>

// LrDistance: out[s,m,n] = invalid ? 100 : |lr[s,m,n] + bilinear(rl[s], gx, gy)|
// grid_sample: padding_mode='zeros', align_corners=False.
//
// R8: persistent 6-row blocks + double-buffered LDS pipeline.
//   - Within a 6-aligned row group, y0(m+1) == y0(m)+1 (floor crossover at
//     m=384 is 6-aligned), so row m's y1-row IS row m+1's y0-row: keep it in
//     registers -> 1 rl row load per output row (was 2).
//   - Double-buffered blended LDS row, ONE __syncthreads per row; next row's
//     rl+lr loads issued right after the barrier so HBM latency hides under
//     the current row's gather/compute.
//   - Per-element math bit-identical to validated R7 (absmax 0.25):
//     ix = fmaf(-d, C1, bx), ds_read2 pair gather, zero-folded y weights.
//   - grid = 2048 blocks (exactly 8 blocks/CU resident), nontemporal lr/out.

constexpr int S = 16;
constexpr int M = 768;
constexpr int N = 1024;
constexpr int ROWS = 6;            // rows per block; 768 % 6 == 0, 384 % 6 == 0
constexpr int BPI = M / ROWS;      // blocks per image = 128
constexpr int LDSTRIDE = N + 16;   // pad past N for the xb+1 read at xb=N-1

typedef float vfloat4 __attribute__((ext_vector_type(4)));

__global__ __launch_bounds__(256, 8) void lr_distance_kernel(
    const float* __restrict__ lr,
    const float* __restrict__ rl,
    float* __restrict__ out)
{
    __shared__ float br[2][LDSTRIDE];   // double-buffered y-blended rl row

    const int blk = blockIdx.x;
    const int s   = blk / BPI;
    const int m0  = (blk - s * BPI) * ROWS;
    const int tid = threadIdx.x;

    const float* rlp = rl + (size_t)s * M * N;

    // --- per-row y interpolation params (block-uniform, reference op order) ---
    auto yrow = [&](int m, float& w0z, float& w1z, int& y0c, int& y1c) {
        const float gy  = (2.0f * (float)m) / (float)(M - 1) - 1.0f;
        const float iy  = ((gy + 1.0f) * (float)M - 1.0f) * 0.5f;
        const float y0f = floorf(iy);
        const float y1f = y0f + 1.0f;
        const float wy1 = iy - y0f;
        const float wy0 = 1.0f - wy1;
        const bool  y0in = (y0f >= 0.0f) && (y0f <= (float)(M - 1));
        const bool  y1in = (y1f >= 0.0f) && (y1f <= (float)(M - 1));
        w0z = y0in ? wy0 : 0.0f;        // zeros-padding folded into weight
        w1z = y1in ? wy1 : 0.0f;
        y0c = min(max((int)y0f, 0), M - 1);
        y1c = min(max((int)y1f, 0), M - 1);
    };

    const int n0 = tid * 4;
    constexpr float C1 = 1024.0f / 1023.0f;
    const float fn0 = (float)n0;                  // exact (int < 2^24)
    const float bx0 = fmaf(fn0, C1, -0.5f);       // ix base for k=0

    // --- prologue: row m0 needs both rl rows; later rows reuse rB -> rA ---
    float w0z, w1z; int y0c, y1c;
    yrow(m0, w0z, w1z, y0c, y1c);
    vfloat4 rA = *reinterpret_cast<const vfloat4*>(rlp + (size_t)y0c * N + n0);
    vfloat4 rB = *reinterpret_cast<const vfloat4*>(rlp + (size_t)y1c * N + n0);
    size_t base = (size_t)(s * M + m0) * N + n0;
    vfloat4 d4 = __builtin_nontemporal_load(
        reinterpret_cast<const vfloat4*>(lr + base));

    if (tid == 0) { br[0][N] = 0.0f; br[1][N] = 0.0f; }  // pair-read pad

    int buf = 0;
#pragma unroll 2
    for (int i = 0; i < ROWS; ++i) {
        // --- stage: blend current rl rows into LDS[buf] ---
        {
            const vfloat4 b = w0z * rA + w1z * rB;
            *reinterpret_cast<vfloat4*>(&br[buf][n0]) = b;
        }
        __syncthreads();   // single barrier per row (double-buffer makes it safe)

        // --- prefetch next row (registers only; overlaps gather below) ---
        vfloat4 nB = {}, nd = {};
        float nw0z = 0.0f, nw1z = 0.0f; int ny0c = 0, ny1c = 0;
        if (i + 1 < ROWS) {
            yrow(m0 + i + 1, nw0z, nw1z, ny0c, ny1c);
            // within the group: y0c(m+1) == y1c(m)  ->  next rA is current rB
            nB = *reinterpret_cast<const vfloat4*>(rlp + (size_t)ny1c * N + n0);
            nd = __builtin_nontemporal_load(
                reinterpret_cast<const vfloat4*>(lr + base + N));
        }

        // --- compute current row from LDS[buf] ---
        const float* bp = br[buf];
        const float dv[4] = {d4.x, d4.y, d4.z, d4.w};
        float ov[4];
#pragma unroll
        for (int k = 0; k < 4; ++k) {
            const float d   = dv[k];
            const float fnk = fn0 + (float)k;          // exact
            const float xr  = fnk - d;                 // bit-exact predicate input
            const float bxk = bx0 + (float)k * C1;
            const float ix  = fmaf(-d, C1, bxk);       // = xr*C1 - 0.5 (±1-2 ulp)
            const float x0f = floorf(ix);
            const float wx1 = ix - x0f;
            const int   x0  = (int)x0f;                // in [-66, 1023]
            const int   xb  = max(x0, 0);              // pair base; xb+1 via pad

            const float p0 = bp[xb];
            const float p1 = bp[xb + 1];               // ds_read2_b32 with p0

            const bool  x0in = (x0 >= 0);
            const bool  x1in = (x0 <= N - 2);
            const float a  = x0in ? p0 : 0.0f;
            float       b  = x0in ? p1 : p0;           // x0=-1 -> x1=0 -> p0
            b = x1in ? b : 0.0f;

            const float warped = fmaf(wx1, b - a, a);  // = wx0*a + wx1*b
            ov[k] = (xr >= 0.0f) ? fabsf(d + warped) : 100.0f;  // xr < N always
        }

        vfloat4 o4;
        o4.x = ov[0]; o4.y = ov[1]; o4.z = ov[2]; o4.w = ov[3];
        __builtin_nontemporal_store(o4, reinterpret_cast<vfloat4*>(out + base));

        // --- rotate pipeline state ---
        rA = rB; rB = nB; d4 = nd;
        w0z = nw0z; w1z = nw1z; y0c = ny0c; y1c = ny1c;
        base += N;
        buf ^= 1;
        // no trailing barrier needed: next write goes to the other buffer, and
        // the write 2 iterations ahead is ordered by the next iteration's barrier
    }
}

extern "C" void kernel_launch(void* const* d_in, const int* in_sizes, int n_in,
                              void* d_out, int out_size, void* d_ws, size_t ws_size,
                              hipStream_t stream) {
    const float* lr  = (const float*)d_in[0];   // disps_lr [16,1,768,1024] fp32
    const float* rl  = (const float*)d_in[1];   // disps_rl [16,1,768,1024] fp32
    float*       out = (float*)d_out;

    const int blocks  = (S * M) / ROWS;  // 2048 persistent-ish blocks, 8/CU
    const int threads = 256;             // 4 elements per thread, one row per iter

    lr_distance_kernel<<<blocks, threads, 0, stream>>>(lr, rl, out);
}